// Round 6
// baseline (593.345 us; speedup 1.0000x reference)
//
#include <hip/hip_runtime.h>
#include <hip/hip_fp16.h>

typedef _Float16 f16x8 __attribute__((ext_vector_type(8)));
typedef _Float16 f16x4 __attribute__((ext_vector_type(4)));
typedef float    f32x4 __attribute__((ext_vector_type(4)));

#define T_STEPS 32
#define NROWS   10000
#define DDIM    256
#define ROWS_PB 48
#define RPB_B   (ROWS_PB * 512)        // 24576 B per f16 tile
#define PB_OFF  (4 * RPB_B)            // Pbuf base (98304)
#define PB_CSTR 192                    // Pbuf bytes per column (48 f32)

// ---------------------------------------------------------------------------
// Pre-kernel: f32 weights -> f16 MFMA B-fragments.
// Fragment (ct,ks), ct=0..15, ks=0..7:
//   dst[((ct*8+ks)*64+lane)*8 + j] = W[ct*16 + (lane&15)][ks*32 + (lane>>4)*8 + j]
// ---------------------------------------------------------------------------
__global__ __launch_bounds__(256) void cvt_weights_kernel(
    const float* __restrict__ Aw, const float* __restrict__ Bw,
    _Float16* __restrict__ wsA, _Float16* __restrict__ wsB)
{
    int tid  = blockIdx.x * 256 + threadIdx.x;      // 0..8191
    int lane = tid & 63;
    int ks   = (tid >> 6) & 7;
    int ct   = tid >> 9;                            // 0..15
    int e     = ct * 16 + (lane & 15);
    int dbase = ks * 32 + (lane >> 4) * 8;
    size_t src = (size_t)e * DDIM + dbase;
    size_t dst = (size_t)tid * 8;
#pragma unroll
    for (int j = 0; j < 8; ++j) {
        wsA[dst + j] = (_Float16)Aw[src + j];
        wsB[dst + j] = (_Float16)Bw[src + j];
    }
}

// Barrier WITHOUT the compiler's vmcnt(0) drain: LDS deps covered by
// lgkmcnt(0); global stores / prefetch loads keep draining across steps.
__device__ __forceinline__ void barrier_lgkm() {
    asm volatile("s_waitcnt lgkmcnt(0)\n\ts_barrier" ::: "memory");
}

// ---------------------------------------------------------------------------
// Fused SSM, K-split. Block = 48 rows x 32 steps. 16 waves = (kh, wc):
// wc in 0..7 owns cols [32wc,32wc+32); kh in {0,1} owns K-half [128kh,+128).
// Each wave reads only HALF the H/S tiles per step (384KB vs 768KB LDS).
// kh=1 writes f32 partials to Pbuf; kh=0 combines after a 2nd lgkm barrier,
// writes S_t (f16) to Sn. Output of step t-1 is stored at the START of step
// t by all waves (full 128B-line f32 stores from LDS readback), fully
// overlapped with compute. Weights in registers (64 regs/lane).
// ---------------------------------------------------------------------------
__global__ __launch_bounds__(1024, 4) void ssm_fused_kernel(
    const float* __restrict__ H,          // [T][N][D] f32
    const _Float16* __restrict__ WaF,     // frag-permuted f16
    const _Float16* __restrict__ WbF,
    const float* __restrict__ bias,       // [D] f32
    float* __restrict__ out)              // [T][N][D] f32
{
    // Hbuf0 | Hbuf1 | Sbuf0 | Sbuf1 (24KB each) | Pbuf (48KB) = 144 KiB
    __shared__ char lds[PB_OFF + 8 * 32 * PB_CSTR];

    const int tid  = threadIdx.x;
    const int lane = tid & 63;
    const int wave = tid >> 6;            // 0..15
    const int wc   = wave & 7;            // 32-col tile
    const int kh   = wave >> 3;           // K-half
    const int lr   = lane & 15;
    const int kg   = lane >> 4;           // 0..3
    const int row0 = blockIdx.x * ROWS_PB;

    // ---- one-time: this wave's weight fragments (K-half only) -> 64 regs ----
    f16x8 wA[2][4], wB[2][4];
#pragma unroll
    for (int et = 0; et < 2; ++et) {
        const int ct = wc * 2 + et;
#pragma unroll
        for (int ks = 0; ks < 4; ++ks) {
            const int ksg = kh * 4 + ks;
            size_t o = (size_t)((ct * 8 + ksg) * 64 + lane) * 8;
            wA[et][ks] = *reinterpret_cast<const f16x8*>(WaF + o);
            wB[et][ks] = *reinterpret_cast<const f16x8*>(WbF + o);
        }
    }

    // rows this wave stages into LDS (3 rows/wave, clamped for tail block)
    int srow[3];
#pragma unroll
    for (int j = 0; j < 3; ++j) {
        int r = row0 + wave * 3 + j;
        srow[j] = (r < NROWS) ? r : (NROWS - 1);
    }

    float bv[2];
#pragma unroll
    for (int et = 0; et < 2; ++et) bv[et] = bias[wc * 32 + et * 16 + lr];

    // ---- prologue: stage H_0 (f32 -> f16, swizzled) into Hbuf0 ----
    f32x4 hreg[3];
#pragma unroll
    for (int j = 0; j < 3; ++j)
        hreg[j] = *reinterpret_cast<const f32x4*>(H + (size_t)srow[j] * DDIM + lane * 4);
#pragma unroll
    for (int j = 0; j < 3; ++j) {
        int r = wave * 3 + j;
        f16x4 v;
#pragma unroll
        for (int k = 0; k < 4; ++k) v[k] = (_Float16)hreg[j][k];
        *reinterpret_cast<f16x4*>(lds + r * 512 + ((lane * 8) ^ ((r & 7) << 4))) = v;
    }
    __syncthreads();

    f32x4 acc[3][2];

    for (int t = 0; t < T_STEPS; ++t) {
        const int cur = t & 1;
        char* Hc = lds + cur * RPB_B;
        char* Hn = lds + (cur ^ 1) * RPB_B;
        char* Sc = lds + 2 * RPB_B + cur * RPB_B;
        char* Sn = lds + 2 * RPB_B + (cur ^ 1) * RPB_B;
        char* Pb = lds + PB_OFF + wc * (32 * PB_CSTR);
        const bool has_next = (t + 1 < T_STEPS);

        // 1. issue next-step H loads (drain under this step's K-loop)
        if (has_next) {
            const float* Ht1 = H + (size_t)(t + 1) * NROWS * DDIM;
#pragma unroll
            for (int j = 0; j < 3; ++j)
                hreg[j] = *reinterpret_cast<const f32x4*>(Ht1 + (size_t)srow[j] * DDIM + lane * 4);
        }

        // 2. store out[t-1] from Sc (S_{t-1}): full 128B-line f32 stores.
        //    Overlaps with this step's compute; lgkm barriers don't wait it.
        if (t > 0) {
            float* Ot = out + (size_t)(t - 1) * NROWS * DDIM;
#pragma unroll
            for (int p = 0; p < 2; ++p) {
                int idx = p * 1024 + tid;
                if (idx < ROWS_PB * 32) {
                    int r   = idx >> 5;
                    int c16 = idx & 31;
                    f16x8 v = *reinterpret_cast<const f16x8*>(
                        Sc + r * 512 + ((c16 * 16) ^ ((r & 7) << 4)));
                    int gr = row0 + r;
                    if (gr < NROWS) {
                        f32x4 lo, hi;
#pragma unroll
                        for (int k = 0; k < 4; ++k) { lo[k] = (float)v[k]; hi[k] = (float)v[k + 4]; }
                        float* dst = Ot + (size_t)gr * DDIM + c16 * 8;
                        *reinterpret_cast<f32x4*>(dst)     = lo;
                        *reinterpret_cast<f32x4*>(dst + 4) = hi;
                    }
                }
            }
        }

        // 3. init acc (bias only on kh=0; kh=1 holds pure partials)
#pragma unroll
        for (int nt = 0; nt < 3; ++nt)
#pragma unroll
            for (int et = 0; et < 2; ++et) {
                float iv = (kh == 0) ? bv[et] : 0.0f;
#pragma unroll
                for (int i = 0; i < 4; ++i) acc[nt][et][i] = iv;
            }

        // 4. K-loop over THIS wave's K-half: 24 LDS reads, 48 MFMAs.
        __builtin_amdgcn_s_setprio(1);
#pragma unroll
        for (int ks = 0; ks < 4; ++ks) {
            const int cbyte = (kh * 4 + ks) * 64 + kg * 16;
            f16x8 hfrag[3];
#pragma unroll
            for (int nt = 0; nt < 3; ++nt) {
                int r = nt * 16 + lr;
                hfrag[nt] = *reinterpret_cast<const f16x8*>(
                    Hc + r * 512 + (cbyte ^ ((r & 7) << 4)));
            }
#pragma unroll
            for (int et = 0; et < 2; ++et)
#pragma unroll
                for (int nt = 0; nt < 3; ++nt)
                    acc[nt][et] = __builtin_amdgcn_mfma_f32_16x16x32_f16(hfrag[nt], wB[et][ks], acc[nt][et], 0, 0, 0);
            if (t > 0) {
                f16x8 sfrag[3];
#pragma unroll
                for (int nt = 0; nt < 3; ++nt) {
                    int r = nt * 16 + lr;
                    sfrag[nt] = *reinterpret_cast<const f16x8*>(
                        Sc + r * 512 + (cbyte ^ ((r & 7) << 4)));
                }
#pragma unroll
                for (int et = 0; et < 2; ++et)
#pragma unroll
                    for (int nt = 0; nt < 3; ++nt)
                        acc[nt][et] = __builtin_amdgcn_mfma_f32_16x16x32_f16(sfrag[nt], wA[et][ks], acc[nt][et], 0, 0, 0);
            }
        }
        __builtin_amdgcn_s_setprio(0);

        // 5. kh=1: publish f32 partials to Pbuf ([col][row], swizzled, b128)
        if (kh == 1) {
#pragma unroll
            for (int nt = 0; nt < 3; ++nt)
#pragma unroll
                for (int et = 0; et < 2; ++et) {
                    int c = et * 16 + lr;                 // col within wc-tile
                    int rb = (nt * 16 + kg * 4) * 4;      // row-byte base (16-aligned)
                    *reinterpret_cast<f32x4*>(
                        Pb + c * PB_CSTR + (rb ^ ((c & 3) << 4))) = acc[nt][et];
                }
        }

        barrier_lgkm();   // barrier B: partials visible

        // 6. kh=0: combine + write S_t (f16) into Sn
        if (kh == 0) {
#pragma unroll
            for (int nt = 0; nt < 3; ++nt)
#pragma unroll
                for (int et = 0; et < 2; ++et) {
                    int c = et * 16 + lr;
                    int rb = (nt * 16 + kg * 4) * 4;
                    f32x4 p = *reinterpret_cast<const f32x4*>(
                        Pb + c * PB_CSTR + (rb ^ ((c & 3) << 4)));
#pragma unroll
                    for (int i = 0; i < 4; ++i) acc[nt][et][i] += p[i];
                    const int gc = wc * 32 + c;           // global col
#pragma unroll
                    for (int i = 0; i < 4; ++i) {
                        int r = nt * 16 + kg * 4 + i;
                        *reinterpret_cast<_Float16*>(
                            Sn + r * 512 + ((gc * 2) ^ ((r & 7) << 4))) = (_Float16)acc[nt][et][i];
                    }
                }
        }

        // 7. all waves: stage H_{t+1} (f16) into Hn (vmcnt wait by data dep)
        if (has_next) {
#pragma unroll
            for (int j = 0; j < 3; ++j) {
                int r = wave * 3 + j;
                f16x4 v;
#pragma unroll
                for (int k = 0; k < 4; ++k) v[k] = (_Float16)hreg[j][k];
                *reinterpret_cast<f16x4*>(Hn + r * 512 + ((lane * 8) ^ ((r & 7) << 4))) = v;
            }
        }

        barrier_lgkm();   // barrier A(next): Sn/Hn visible
    }

    // ---- final epilogue: store out[31] from S_31 (in Sbuf0 after t=31) ----
    {
        char* Sf = lds + 2 * RPB_B;       // (31+1)&1 == 0
        float* Ot = out + (size_t)(T_STEPS - 1) * NROWS * DDIM;
#pragma unroll
        for (int p = 0; p < 2; ++p) {
            int idx = p * 1024 + tid;
            if (idx < ROWS_PB * 32) {
                int r   = idx >> 5;
                int c16 = idx & 31;
                f16x8 v = *reinterpret_cast<const f16x8*>(
                    Sf + r * 512 + ((c16 * 16) ^ ((r & 7) << 4)));
                int gr = row0 + r;
                if (gr < NROWS) {
                    f32x4 lo, hi;
#pragma unroll
                    for (int k = 0; k < 4; ++k) { lo[k] = (float)v[k]; hi[k] = (float)v[k + 4]; }
                    float* dst = Ot + (size_t)gr * DDIM + c16 * 8;
                    *reinterpret_cast<f32x4*>(dst)     = lo;
                    *reinterpret_cast<f32x4*>(dst + 4) = hi;
                }
            }
        }
    }
}

extern "C" void kernel_launch(void* const* d_in, const int* in_sizes, int n_in,
                              void* d_out, int out_size, void* d_ws, size_t ws_size,
                              hipStream_t stream)
{
    const float* H  = (const float*)d_in[0];
    const float* Aw = (const float*)d_in[1];
    const float* Bw = (const float*)d_in[2];
    const float* Bb = (const float*)d_in[3];
    float* out      = (float*)d_out;

    _Float16* wsA = (_Float16*)d_ws;         // 128 KiB
    _Float16* wsB = wsA + 65536;             // 128 KiB

    cvt_weights_kernel<<<32, 256, 0, stream>>>(Aw, Bw, wsA, wsB);

    int nblocks = (NROWS + ROWS_PB - 1) / ROWS_PB;   // 209 (< 256 CUs, 1 round)
    ssm_fused_kernel<<<nblocks, 1024, 0, stream>>>(H, wsA, wsB, Bb, out);
}

// Round 7
// 227.526 us; speedup vs baseline: 2.6078x; 2.6078x over previous
//
#include <hip/hip_runtime.h>
#include <hip/hip_fp16.h>

typedef _Float16 f16x8 __attribute__((ext_vector_type(8)));
typedef _Float16 f16x4 __attribute__((ext_vector_type(4)));
typedef float    f32x4 __attribute__((ext_vector_type(4)));

#define T_STEPS 32
#define NROWS   10000
#define DDIM    256
#define ROWS_PB 40                     // 250 blocks exactly (10000/40), no tail
#define TILE_ROWS 48                   // LDS tile kept at 48 rows (8 pad rows)
#define TILE_B  (TILE_ROWS * 512)      // 24576 B per f16 tile
#define NCHUNK4 (ROWS_PB * DDIM / 4)   // 2560 f32x4 chunks per H slab
#define NCHUNK16 (ROWS_PB * 32)        // 1280 16B chunks per S tile (real rows)

// ---------------------------------------------------------------------------
// Pre-kernel: f32 weights -> f16 MFMA B-fragments.
// Fragment (ct,ks), ct=0..15, ks=0..7:
//   dst[((ct*8+ks)*64+lane)*8 + j] = W[ct*16 + (lane&15)][ks*32 + (lane>>4)*8 + j]
// ---------------------------------------------------------------------------
__global__ __launch_bounds__(256) void cvt_weights_kernel(
    const float* __restrict__ Aw, const float* __restrict__ Bw,
    _Float16* __restrict__ wsA, _Float16* __restrict__ wsB)
{
    int tid  = blockIdx.x * 256 + threadIdx.x;      // 0..8191
    int lane = tid & 63;
    int ks   = (tid >> 6) & 7;
    int ct   = tid >> 9;                            // 0..15
    int e     = ct * 16 + (lane & 15);
    int dbase = ks * 32 + (lane >> 4) * 8;
    size_t src = (size_t)e * DDIM + dbase;
    size_t dst = (size_t)tid * 8;
#pragma unroll
    for (int j = 0; j < 8; ++j) {
        wsA[dst + j] = (_Float16)Aw[src + j];
        wsB[dst + j] = (_Float16)Bw[src + j];
    }
}

// Barrier WITHOUT the compiler's vmcnt(0) drain: LDS deps are covered by
// lgkmcnt(0); global stores / prefetch loads keep draining across steps.
__device__ __forceinline__ void barrier_lgkm() {
    asm volatile("s_waitcnt lgkmcnt(0)\n\ts_barrier" ::: "memory");
}

// ---------------------------------------------------------------------------
// Fused SSM (R4 schedule, 40-row blocks). Block = 40 rows x 32 steps.
// 16 waves; wave w owns cols [16w,16w+16). Weights in registers (64/lane).
// Double-buffered LDS H tile + S exchange (48-row tiles, rows 40-47 are
// dead padding: junk there only ever affects pad-row outputs, never stored).
// ONE lgkm-only barrier per step; out[t] stored from LDS readback with full
// 128B-line f32x4 stores after the barrier.
// ---------------------------------------------------------------------------
__global__ __launch_bounds__(1024, 4) void ssm_fused_kernel(
    const float* __restrict__ H,          // [T][N][D] f32
    const _Float16* __restrict__ WaF,     // frag-permuted f16
    const _Float16* __restrict__ WbF,
    const float* __restrict__ bias,       // [D] f32
    float* __restrict__ out)              // [T][N][D] f32
{
    // Hbuf0 | Hbuf1 | Sbuf0 | Sbuf1, each 24 KiB (96 KiB total)
    __shared__ char lds[4 * TILE_B];

    const int tid  = threadIdx.x;
    const int lane = tid & 63;
    const int wave = tid >> 6;            // 0..15 == ct (16-col tile)
    const int lr   = lane & 15;
    const int kg   = lane >> 4;           // 0..3
    const int row0 = blockIdx.x * ROWS_PB;
    const bool third = (tid < NCHUNK4 - 2048);   // tid < 512: owns a 3rd chunk

    // ---- one-time: this wave's weight fragments -> 64 VGPRs ----
    f16x8 wA[8], wB[8];
#pragma unroll
    for (int ks = 0; ks < 8; ++ks) {
        size_t o = (size_t)((wave * 8 + ks) * 64 + lane) * 8;
        wA[ks] = *reinterpret_cast<const f16x8*>(WaF + o);
        wB[ks] = *reinterpret_cast<const f16x8*>(WbF + o);
    }

    const float bv = bias[wave * 16 + lr];

    // Block's H slab at step t is contiguous: H + t*N*D + row0*D, 40960 floats.
    const float* Hslab = H + (size_t)row0 * DDIM;

    // ---- prologue: stage H_0 (f32 -> f16, swizzled) into Hbuf0 ----
    // flat chunks: idx in [0,2560); r = idx>>6, f16-byte = (idx&63)*8
    f32x4 hreg[3];
#pragma unroll
    for (int j = 0; j < 3; ++j) {
        int idx = j * 1024 + tid;
        if (j < 2 || third)
            hreg[j] = *reinterpret_cast<const f32x4*>(Hslab + (size_t)idx * 4);
    }
#pragma unroll
    for (int j = 0; j < 3; ++j) {
        int idx = j * 1024 + tid;
        if (j < 2 || third) {
            int r = idx >> 6;
            f16x4 v;
#pragma unroll
            for (int k = 0; k < 4; ++k) v[k] = (_Float16)hreg[j][k];
            *reinterpret_cast<f16x4*>(lds + r * 512 + (((idx & 63) * 8) ^ ((r & 7) << 4))) = v;
        }
    }
    __syncthreads();

    f32x4 acc[3];

    for (int t = 0; t < T_STEPS; ++t) {
        const int cur = t & 1;
        char* Hc = lds + cur * TILE_B;
        char* Hn = lds + (cur ^ 1) * TILE_B;
        char* Sc = lds + 2 * TILE_B + cur * TILE_B;
        char* Sn = lds + 2 * TILE_B + (cur ^ 1) * TILE_B;
        const bool has_next = (t + 1 < T_STEPS);

        // 1. issue next-step H loads (hidden under this step's K-loop)
        if (has_next) {
            const float* Ht1 = Hslab + (size_t)(t + 1) * NROWS * DDIM;
#pragma unroll
            for (int j = 0; j < 3; ++j) {
                int idx = j * 1024 + tid;
                if (j < 2 || third)
                    hreg[j] = *reinterpret_cast<const f32x4*>(Ht1 + (size_t)idx * 4);
            }
        }

        // 2. init acc with bias (C/D: col = lane&15)
#pragma unroll
        for (int nt = 0; nt < 3; ++nt)
#pragma unroll
            for (int i = 0; i < 4; ++i) acc[nt][i] = bv;

        // 3. K-loop: acc += H_t@Wb^T (+ S_{t-1}@Wa^T for t>0). LDS+MFMA only.
        __builtin_amdgcn_s_setprio(1);
#pragma unroll
        for (int ks = 0; ks < 8; ++ks) {
            const int cbyte = ks * 64 + kg * 16;
            f16x8 hfrag[3];
#pragma unroll
            for (int nt = 0; nt < 3; ++nt) {
                int r = nt * 16 + lr;
                hfrag[nt] = *reinterpret_cast<const f16x8*>(
                    Hc + r * 512 + (cbyte ^ ((r & 7) << 4)));
            }
#pragma unroll
            for (int nt = 0; nt < 3; ++nt)
                acc[nt] = __builtin_amdgcn_mfma_f32_16x16x32_f16(hfrag[nt], wB[ks], acc[nt], 0, 0, 0);
            if (t > 0) {
                f16x8 sfrag[3];
#pragma unroll
                for (int nt = 0; nt < 3; ++nt) {
                    int r = nt * 16 + lr;
                    sfrag[nt] = *reinterpret_cast<const f16x8*>(
                        Sc + r * 512 + (cbyte ^ ((r & 7) << 4)));
                }
#pragma unroll
                for (int nt = 0; nt < 3; ++nt)
                    acc[nt] = __builtin_amdgcn_mfma_f32_16x16x32_f16(sfrag[nt], wA[ks], acc[nt], 0, 0, 0);
            }
        }
        __builtin_amdgcn_s_setprio(0);

        // 4a. stage H_{t+1} (f16) into Hn (vmcnt waits happen here by dep)
        if (has_next) {
#pragma unroll
            for (int j = 0; j < 3; ++j) {
                int idx = j * 1024 + tid;
                if (j < 2 || third) {
                    int r = idx >> 6;
                    f16x4 v;
#pragma unroll
                    for (int k = 0; k < 4; ++k) v[k] = (_Float16)hreg[j][k];
                    *reinterpret_cast<f16x4*>(Hn + r * 512 + (((idx & 63) * 8) ^ ((r & 7) << 4))) = v;
                }
            }
        }

        // 4b. S_t -> Sn (f16, swizzled). Rows 40-47 are pad (never stored).
#pragma unroll
        for (int nt = 0; nt < 3; ++nt) {
            const int c = wave * 16 + lr;
#pragma unroll
            for (int i = 0; i < 4; ++i) {
                int r = nt * 16 + kg * 4 + i;
                *reinterpret_cast<_Float16*>(Sn + r * 512 + ((c * 2) ^ ((r & 7) << 4))) =
                    (_Float16)acc[nt][i];
            }
        }

        // 5. single lgkm-only barrier: Sn/Hn complete & visible; global
        //    stores keep draining in the background.
        barrier_lgkm();

        // 6. epilogue: row-contiguous readback of Sn -> coalesced f32 stores.
        //    1280 chunks of 16B (40 real rows x 32 chunks/row).
        float* Ot = out + (size_t)t * NROWS * DDIM;
#pragma unroll
        for (int p = 0; p < 2; ++p) {
            int idx = p * 1024 + tid;
            if (idx < NCHUNK16) {
                int r   = idx >> 5;                // 0..39 (real rows only)
                int c16 = idx & 31;                // 16B chunk within row
                f16x8 v = *reinterpret_cast<const f16x8*>(
                    Sn + r * 512 + ((c16 * 16) ^ ((r & 7) << 4)));
                int gr = row0 + r;
                f32x4 lo, hi;
#pragma unroll
                for (int k = 0; k < 4; ++k) { lo[k] = (float)v[k]; hi[k] = (float)v[k + 4]; }
                float* dst = Ot + (size_t)gr * DDIM + c16 * 8;
                *reinterpret_cast<f32x4*>(dst)     = lo;
                *reinterpret_cast<f32x4*>(dst + 4) = hi;
            }
        }
        // no second barrier: next step's LDS writes target the opposite
        // buffers; this epilogue's reads complete before this wave's next
        // lgkmcnt(0)+barrier, which precedes any conflicting write (t+2).
    }
}

extern "C" void kernel_launch(void* const* d_in, const int* in_sizes, int n_in,
                              void* d_out, int out_size, void* d_ws, size_t ws_size,
                              hipStream_t stream)
{
    const float* H  = (const float*)d_in[0];
    const float* Aw = (const float*)d_in[1];
    const float* Bw = (const float*)d_in[2];
    const float* Bb = (const float*)d_in[3];
    float* out      = (float*)d_out;

    _Float16* wsA = (_Float16*)d_ws;         // 128 KiB
    _Float16* wsB = wsA + 65536;             // 128 KiB

    cvt_weights_kernel<<<32, 256, 0, stream>>>(Aw, Bw, wsA, wsB);

    int nblocks = NROWS / ROWS_PB;           // 250 (10000/40, exact)
    ssm_fused_kernel<<<nblocks, 1024, 0, stream>>>(H, wsA, wsB, Bb, out);
}